// Round 4
// baseline (10634.953 us; speedup 1.0000x reference)
//
#include <hip/hip_runtime.h>
#include <hip/hip_bf16.h>

typedef __attribute__((ext_vector_type(8))) short bf16x8;
typedef __attribute__((ext_vector_type(4))) float f32x4;

#define HID 1024
#define BATCH 32
#define NACT (BATCH * HID)        // 32768
#define NWIH (3 * 3 * HID * HID)  // plane stride (all layers)
#define LSTRIDE (3 * HID * HID)
#define NFC (2500 * HID)
#define NP 3
#define NBLK 64
#define TSTEPS 64

__device__ __forceinline__ f32x4 mfma16(bf16x8 a, bf16x8 b, f32x4 c) {
  return __builtin_amdgcn_mfma_f32_16x16x32_bf16(a, b, c, 0, 0, 0);
}

__device__ __forceinline__ __hip_bfloat16 bf_from_bits(unsigned short u) {
  union { unsigned short s; __hip_bfloat16 b; } cv; cv.s = u; return cv.b;
}

// Exact 3-plane split of fp32 into bf16 planes (8+8+8 mantissa bits).
__device__ __forceinline__ void split_store(float v, __hip_bfloat16* base, int stride, int idx) {
  float r = v;
#pragma unroll
  for (int p = 0; p < NP; ++p) {
    __hip_bfloat16 pb;
    if (p == NP - 1) pb = __float2bfloat16(r);
    else pb = bf_from_bits((unsigned short)(__float_as_uint(r) >> 16));
    base[p * stride + idx] = pb;
    r -= __bfloat162float(pb);
  }
}

// ---------------- weight split fp32 -> 3 bf16 planes (once per launch) ----------------
__global__ void convert_weights(const float* __restrict__ Wih, const float* __restrict__ Whh,
                                const float* __restrict__ fcw,
                                __hip_bfloat16* __restrict__ WIHP, __hip_bfloat16* __restrict__ WHHP,
                                __hip_bfloat16* __restrict__ FCWP) {
  int i0 = blockIdx.x * blockDim.x + threadIdx.x;
  int st = gridDim.x * blockDim.x;
  for (int i = i0; i < NWIH; i += st) {
    split_store(Wih[i], WIHP, NWIH, i);
    split_store(Whh[i], WHHP, NWIH, i);
  }
  for (int i = i0; i < NFC; i += st) split_store(fcw[i], FCWP, NFC, i);
}

// ---------------- setup: zero h set0, split x -> XBP, trig tables, zero barrier ----------------
__global__ void setup_kernel(const float* __restrict__ x_in, float* __restrict__ h0,
                             __hip_bfloat16* __restrict__ hbp0, __hip_bfloat16* __restrict__ xbp,
                             float* __restrict__ cosM, float* __restrict__ sinM,
                             unsigned long long* __restrict__ barcnt) {
  int i0 = blockIdx.x * blockDim.x + threadIdx.x;
  int st = gridDim.x * blockDim.x;
  if (i0 == 0) *barcnt = 0ull;
  for (int k = i0; k < 3 * NACT; k += st) h0[k] = 0.0f;
  for (int k = i0; k < 3 * NP * NACT; k += st) hbp0[k] = bf_from_bits(0);
  for (int k = i0; k < NACT; k += st) split_store(x_in[k], xbp, NACT, k);
  for (int k = i0; k < 32 * 50; k += st) {
    int a = k / 50, n = k % 50;
    int ka = (a + 34) % 50;  // fftshift+crop: kept row a is frequency (a+34)%50
    int ph = (ka * n) % 50;  // exact integer angle reduction
    float ang = 6.283185307179586f * (float)ph / 50.0f;
    cosM[k] = cosf(ang);
    sinM[k] = sinf(ang);
  }
}

// ---------------- grid barrier: monotonic counter, device(agent)-scope ----------------
__device__ __forceinline__ void gbar(unsigned long long* cnt, unsigned long long tgt) {
  __syncthreads();  // all block stores drained to L2 (barrier implies vmcnt(0))
  if (threadIdx.x == 0) {
    __threadfence();  // release: write back this XCD's L2 to coherence point
    __hip_atomic_fetch_add(cnt, 1ull, __ATOMIC_RELAXED, __HIP_MEMORY_SCOPE_AGENT);
    while (__hip_atomic_load(cnt, __ATOMIC_RELAXED, __HIP_MEMORY_SCOPE_AGENT) < tgt)
      __builtin_amdgcn_s_sleep(2);
    __threadfence();  // acquire: invalidate stale L1/L2 before consuming peers' data
  }
  __syncthreads();
}

// ---------------- persistent kernel: 64 steps x (3 GRU + FC + DFT) ----------------
__global__ __launch_bounds__(256) void rnn_persistent(
    const __hip_bfloat16* __restrict__ WIHP, const __hip_bfloat16* __restrict__ WHHP,
    const __hip_bfloat16* __restrict__ FCWP,
    const float* __restrict__ b_ih, const float* __restrict__ b_hh,
    const float* __restrict__ fc_b,
    float* __restrict__ H,             // [2][3][NACT] fp32
    __hip_bfloat16* __restrict__ HBP,  // [2][3][NP][NACT]
    __hip_bfloat16* __restrict__ XBP,  // [NP][NACT]
    const float* __restrict__ cosM, const float* __restrict__ sinM,
    float* __restrict__ dout,          // [64][32][2500]
    unsigned long long* __restrict__ barcnt) {
  __shared__ float smem[9216];  // GRU reduce 3*64*48 | FC reduce | DFT scratch (8900)
  const int tid = threadIdx.x;
  const int L = tid & 63, w = tid >> 6;
  const int col = L & 15, quad = L >> 4;
  const int kb = w * 256, aoff = quad * 8;
  const int bid = blockIdx.x;
  const f32x4 zero = {0.f, 0.f, 0.f, 0.f};
  unsigned long long tgt = 0;

#pragma unroll 1
  for (int t = 0; t < TSTEPS; ++t) {
    const int pi = t & 1, po = pi ^ 1;
#pragma unroll 1
    for (int l = 0; l < 3; ++l) {
      // ================= GRU layer phase (all 64 blocks; j-tile = bid*16) =================
      const __hip_bfloat16* Wih = WIHP + (size_t)l * LSTRIDE;
      const __hip_bfloat16* Whh = WHHP + (size_t)l * LSTRIDE;
      const __hip_bfloat16* Ain = (l == 0) ? XBP : (HBP + (size_t)((po * 3 + (l - 1)) * NP) * NACT);
      const __hip_bfloat16* hb_in = HBP + (size_t)((pi * 3 + l) * NP) * NACT;
      const float* h_in = H + (size_t)(pi * 3 + l) * NACT;
      float* h_out = H + (size_t)(po * 3 + l) * NACT;
      __hip_bfloat16* hb_out = HBP + (size_t)((po * 3 + l) * NP) * NACT;
      const float* bih = b_ih + l * 3 * HID;
      const float* bhh = b_hh + l * 3 * HID;
      const int jt = bid * 16;

      f32x4 accI[3][2], accH[3][2];
#pragma unroll
      for (int g = 0; g < 3; ++g)
#pragma unroll
        for (int mh = 0; mh < 2; ++mh) { accI[g][mh] = zero; accH[g][mh] = zero; }

      for (int it = 0; it < 8; ++it) {
        int k0 = kb + it * 32 + aoff;
        bf16x8 xa[NP][2], ha[NP][2], bi[NP][3], bh[NP][3];
#pragma unroll
        for (int mh = 0; mh < 2; ++mh) {
          int r = (mh * 16 + col) * HID + k0;
#pragma unroll
          for (int p = 0; p < NP; ++p) {
            xa[p][mh] = *(const bf16x8*)(Ain + p * NACT + r);
            ha[p][mh] = *(const bf16x8*)(hb_in + p * NACT + r);
          }
        }
#pragma unroll
        for (int g = 0; g < 3; ++g) {
          int rr = (g * HID + jt + col) * HID + k0;  // B^T: row = output feature j
#pragma unroll
          for (int p = 0; p < NP; ++p) {
            bi[p][g] = *(const bf16x8*)(Wih + p * NWIH + rr);
            bh[p][g] = *(const bf16x8*)(Whh + p * NWIH + rr);
          }
        }
#pragma unroll
        for (int g = 0; g < 3; ++g)
#pragma unroll
          for (int mh = 0; mh < 2; ++mh)
#pragma unroll
            for (int p = 0; p < NP; ++p)
#pragma unroll
              for (int q = 0; q < NP - p; ++q) {  // plane pairs p+q <= 2
                accI[g][mh] = mfma16(xa[p][mh], bi[q][g], accI[g][mh]);
                accH[g][mh] = mfma16(ha[p][mh], bh[q][g], accH[g][mh]);
              }
      }

      if (w > 0) {
        float* p = &smem[((w - 1) * 64 + L) * 48];
#pragma unroll
        for (int g = 0; g < 3; ++g)
#pragma unroll
          for (int mh = 0; mh < 2; ++mh) {
            *(f32x4*)(p + (g * 2 + mh) * 4) = accI[g][mh];
            *(f32x4*)(p + 24 + (g * 2 + mh) * 4) = accH[g][mh];
          }
      }
      __syncthreads();
      if (w == 0) {
#pragma unroll
        for (int s = 0; s < 3; ++s) {
          const float* p = &smem[(s * 64 + L) * 48];
#pragma unroll
          for (int g = 0; g < 3; ++g)
#pragma unroll
            for (int mh = 0; mh < 2; ++mh) {
              accI[g][mh] += *(const f32x4*)(p + (g * 2 + mh) * 4);
              accH[g][mh] += *(const f32x4*)(p + 24 + (g * 2 + mh) * 4);
            }
        }
        int j = jt + col;
        float bI[3], bH[3];
#pragma unroll
        for (int g = 0; g < 3; ++g) { bI[g] = bih[g * HID + j]; bH[g] = bhh[g * HID + j]; }
#pragma unroll
        for (int mh = 0; mh < 2; ++mh) {
#pragma unroll
          for (int r = 0; r < 4; ++r) {
            int b = mh * 16 + quad * 4 + r;  // C/D map: row -> batch, col -> feature
            float ir = accI[0][mh][r] + bI[0];
            float iz = accI[1][mh][r] + bI[1];
            float in_ = accI[2][mh][r] + bI[2];
            float hr = accH[0][mh][r] + bH[0];
            float hz = accH[1][mh][r] + bH[1];
            float hn = accH[2][mh][r] + bH[2];
            float rr = 1.0f / (1.0f + expf(-(ir + hr)));
            float zz = 1.0f / (1.0f + expf(-(iz + hz)));
            float nn = tanhf(in_ + rr * hn);
            float hold = h_in[b * HID + j];
            float hnew = (1.0f - zz) * nn + zz * hold;
            h_out[b * HID + j] = hnew;
            split_store(hnew, hb_out, NACT, b * HID + j);
          }
        }
      }
      tgt += NBLK;
      gbar(barcnt, tgt);
    }

    // ================= FC phase: out = h2 @ fc_w^T + fc_b -> dout slice =================
    {
      float* outp = dout + (size_t)t * BATCH * 2500;
      const __hip_bfloat16* h2p = HBP + (size_t)((po * 3 + 2) * NP) * NACT;
#pragma unroll 1
      for (int tt = bid; tt < 157; tt += NBLK) {
        int jt2 = tt * 16;
        int row = jt2 + col;
        int rowc = row < 2500 ? row : 2499;
        f32x4 acc0 = zero, acc1 = zero;
        for (int it = 0; it < 8; ++it) {
          int k0 = kb + it * 32 + aoff;
          bf16x8 a0[NP], a1[NP], bb[NP];
#pragma unroll
          for (int p = 0; p < NP; ++p) {
            a0[p] = *(const bf16x8*)(h2p + p * NACT + col * HID + k0);
            a1[p] = *(const bf16x8*)(h2p + p * NACT + (16 + col) * HID + k0);
            bb[p] = *(const bf16x8*)(FCWP + p * NFC + rowc * HID + k0);
          }
#pragma unroll
          for (int p = 0; p < NP; ++p)
#pragma unroll
            for (int q = 0; q < NP - p; ++q) {
              acc0 = mfma16(a0[p], bb[q], acc0);
              acc1 = mfma16(a1[p], bb[q], acc1);
            }
        }
        __syncthreads();  // previous tile's reduce reads done before overwrite
        if (w > 0) {
          float* p = &smem[((w - 1) * 64 + L) * 8];
          *(f32x4*)p = acc0;
          *(f32x4*)(p + 4) = acc1;
        }
        __syncthreads();
        if (w == 0) {
#pragma unroll
          for (int s = 0; s < 3; ++s) {
            const float* p = &smem[(s * 64 + L) * 8];
            acc0 += *(const f32x4*)p;
            acc1 += *(const f32x4*)(p + 4);
          }
          int j = jt2 + col;
          if (j < 2500) {
            float bias = fc_b[j];
#pragma unroll
            for (int r = 0; r < 4; ++r) {
              int b = quad * 4 + r;
              outp[b * 2500 + j] = acc0[r] + bias;
              outp[(16 + b) * 2500 + j] = acc1[r] + bias;
            }
          }
        }
      }
      tgt += NBLK;
      gbar(barcnt, tgt);
    }

    // ================= DFT phase: x_next = C out C^T - S out S^T (blocks 0..31) =========
    if (bid < 32) {
      const float* outp = dout + (size_t)t * BATCH * 2500 + (size_t)bid * 2500;
      float* sq = smem;              // 2500
      float* cA = smem + 2500;       // 1600
      float* sA = smem + 4100;       // 1600
      float* Tm = smem + 5700;       // 1600
      float* Um = smem + 7300;       // 1600 (ends 8900)
      for (int i = tid; i < 2500; i += 256) sq[i] = outp[i];
      for (int i = tid; i < 1600; i += 256) { cA[i] = cosM[i]; sA[i] = sinM[i]; }
      __syncthreads();
      for (int idx = tid; idx < 1600; idx += 256) {
        int a = idx / 50, n2 = idx % 50;
        float ta = 0.f, ua = 0.f;
        for (int n1 = 0; n1 < 50; ++n1) {
          float v = sq[n1 * 50 + n2];
          ta += v * cA[a * 50 + n1];
          ua += v * sA[a * 50 + n1];
        }
        Tm[idx] = ta;
        Um[idx] = ua;
      }
      __syncthreads();
      for (int idx = tid; idx < 1024; idx += 256) {
        int a = idx >> 5, c = idx & 31;
        float acc = 0.f;
        for (int n2 = 0; n2 < 50; ++n2)
          acc += Tm[a * 50 + n2] * cA[c * 50 + n2] - Um[a * 50 + n2] * sA[c * 50 + n2];
        split_store(acc, XBP, NACT, bid * HID + idx);
      }
    }
    if (t < TSTEPS - 1) {
      tgt += NBLK;
      gbar(barcnt, tgt);
    }
  }
}

extern "C" void kernel_launch(void* const* d_in, const int* in_sizes, int n_in,
                              void* d_out, int out_size, void* d_ws, size_t ws_size,
                              hipStream_t stream) {
  const float* x_in = (const float*)d_in[0];
  const float* W_ih = (const float*)d_in[1];
  const float* W_hh = (const float*)d_in[2];
  const float* b_ih = (const float*)d_in[3];
  const float* b_hh = (const float*)d_in[4];
  const float* fc_w = (const float*)d_in[5];
  const float* fc_b = (const float*)d_in[6];
  float* dout = (float*)d_out;
  char* ws = (char*)d_ws;

  // workspace layout (bytes)
  __hip_bfloat16* WIHP = (__hip_bfloat16*)(ws + 0);            // 56,623,104
  __hip_bfloat16* WHHP = (__hip_bfloat16*)(ws + 56623104);     // 56,623,104
  __hip_bfloat16* FCWP = (__hip_bfloat16*)(ws + 113246208);    // 15,360,000
  float* H = (float*)(ws + 128606208);                         // 786,432
  __hip_bfloat16* HBP = (__hip_bfloat16*)(ws + 129392640);     // 1,179,648
  __hip_bfloat16* XBP = (__hip_bfloat16*)(ws + 130572288);     // 196,608
  float* COSM = (float*)(ws + 130768896);                      // 6,400
  float* SINM = (float*)(ws + 130775296);                      // 6,400
  unsigned long long* BAR = (unsigned long long*)(ws + 130781696);

  convert_weights<<<2048, 256, 0, stream>>>(W_ih, W_hh, fc_w, WIHP, WHHP, FCWP);
  setup_kernel<<<512, 256, 0, stream>>>(x_in, H, HBP, XBP, COSM, SINM, BAR);
  rnn_persistent<<<NBLK, 256, 0, stream>>>(WIHP, WHHP, FCWP, b_ih, b_hh, fc_b,
                                           H, HBP, XBP, COSM, SINM, dout, BAR);
}